// Round 1
// baseline (10901.909 us; speedup 1.0000x reference)
//
#include <hip/hip_runtime.h>

#define NB 4
#define NPTS 8192
#define KNN 16
#define PTS (NB*NPTS)
#define CHUNK 2048

__device__ __forceinline__ float lrelu(float x){ return x >= 0.f ? x : 0.1f*x; }

// ---------------- xyz fill: writes xyz into first 3 cols of fT1/fT2 rows ----
__global__ __launch_bounds__(256) void xyz_fill_kernel(
    const float* __restrict__ xyz, float* __restrict__ fT1, float* __restrict__ fT2){
  long g = (long)blockIdx.x*256 + threadIdx.x;  // 0..32767
  int b = (int)(g >> 13), n = (int)(g & 8191);
  #pragma unroll
  for (int j = 0; j < 3; ++j){
    float v = xyz[((long)b*3 + j)*NPTS + n];
    fT1[g*264 + j] = v;
    fT2[g*136 + j] = v;
  }
}

// ---------------- transpose feat [B][256][N] -> fT1 rows [b*N+n][3+c] -------
__global__ __launch_bounds__(256) void transpose_feat_kernel(
    const float* __restrict__ feat, float* __restrict__ fT1){
  __shared__ float tile[64][65];
  int bx = blockIdx.x;           // n-tile (128)
  int by = blockIdx.y;           // c-tile (4)
  int bz = blockIdx.z;           // batch (4)
  int t = threadIdx.x;
  int x = t & 63, y4 = t >> 6;
  const float* src = feat + ((long)bz*256 + by*64)*NPTS + (long)bx*64;
  #pragma unroll
  for (int i = 0; i < 16; ++i){
    int c = y4 + i*4;
    tile[c][x] = src[(long)c*NPTS + x];
  }
  __syncthreads();
  float* dst = fT1 + ((long)bz*NPTS + (long)bx*64)*264 + 3 + (long)by*64;
  #pragma unroll
  for (int i = 0; i < 16; ++i){
    int r = y4 + i*4;
    dst[(long)r*264 + x] = tile[x][r];
  }
}

// ---------------- aggregation: one wave per point ---------------------------
// fT rows: [0..2]=xyz, [3..CTOT-1]=features. Produces agg row [KP] (f = c*8+m).
template<int CTOT, int S, int KP>
__global__ __launch_bounds__(256) void agg_kernel(
    const float* __restrict__ fT, const int* __restrict__ knn,
    const float* __restrict__ w_wn, const float* __restrict__ b_wn,
    float* __restrict__ aggout, int chunk_base){
  int wave = threadIdx.x >> 6;
  int lane = threadIdx.x & 63;
  long p_local = (long)blockIdx.x*4 + wave;      // 0..CHUNK-1
  long g = chunk_base + p_local;
  int b = (int)(g >> 13), n = (int)(g & 8191);
  const float* crow = fT + g * S;
  float cx = crow[0], cy = crow[1], cz = crow[2];
  float wm[8][3], bm[8];
  #pragma unroll
  for (int m = 0; m < 8; ++m){
    wm[m][0] = w_wn[m*3+0]; wm[m][1] = w_wn[m*3+1]; wm[m][2] = w_wn[m*3+2];
    bm[m] = b_wn[m];
  }
  int idx_lane = knn[(((long)b<<13) + n)*KNN + (lane & 15)];
  constexpr int NS = (CTOT + 63)/64;
  float acc[NS][8];
  #pragma unroll
  for (int s = 0; s < NS; ++s)
    #pragma unroll
    for (int m = 0; m < 8; ++m) acc[s][m] = 0.f;

  for (int k = 0; k < 16; ++k){
    int idx = __shfl(idx_lane, k);
    const float* nr = fT + (((long)b<<13) + idx)*S;
    float px = nr[0]-cx, py = nr[1]-cy, pz = nr[2]-cz;
    float wk[8];
    #pragma unroll
    for (int m = 0; m < 8; ++m){
      float v = wm[m][0]*px + wm[m][1]*py + wm[m][2]*pz + bm[m];
      wk[m] = lrelu(v);
    }
    #pragma unroll
    for (int s = 0; s < NS; ++s){
      int c = lane + s*64;
      if (c < CTOT){
        float fg = nr[c];
        #pragma unroll
        for (int m = 0; m < 8; ++m) acc[s][m] += fg * wk[m];
      }
    }
  }
  float* outrow = aggout + p_local * KP;
  #pragma unroll
  for (int s = 0; s < NS; ++s){
    int c = lane + s*64;
    if (c < CTOT){
      float4 v0 = make_float4(acc[s][0], acc[s][1], acc[s][2], acc[s][3]);
      float4 v1 = make_float4(acc[s][4], acc[s][5], acc[s][6], acc[s][7]);
      *(float4*)&outrow[c*8 + 0] = v0;
      *(float4*)&outrow[c*8 + 4] = v1;
    }
  }
  if (lane < KP - CTOT*8) outrow[CTOT*8 + lane] = 0.f;
}

// ---------------- GEMM: [M x KP(padded,K zero-padded)] @ W[128][KREAL]^T ----
// out[g*row_stride + col_off + o] = lrelu(sum + bias[o]); 64 pts x 128 outs/block.
template<int KP, int KREAL>
__global__ __launch_bounds__(256) void lin_kernel(
    const float* __restrict__ aggp, const float* __restrict__ W,
    const float* __restrict__ bias, float* __restrict__ outp,
    long row_stride, int col_off, long chunk_base){
  __shared__ __align__(16) float As[64][33];
  __shared__ __align__(16) float Bs[32][132];
  int t = threadIdx.x;
  int m0 = blockIdx.x * 64;
  int tm = t >> 4, tn = t & 15;
  float acc[4][8];
  #pragma unroll
  for (int i = 0; i < 4; ++i)
    #pragma unroll
    for (int j = 0; j < 8; ++j) acc[i][j] = 0.f;

  for (int kc = 0; kc < KP/32; ++kc){
    #pragma unroll
    for (int r = 0; r < 8; ++r){
      int idx = t + r*256;
      int pt = idx >> 5, kk = idx & 31;
      As[pt][kk] = aggp[(long)(m0+pt)*KP + kc*32 + kk];
    }
    #pragma unroll
    for (int r = 0; r < 16; ++r){
      int idx = t + r*256;
      int o = idx >> 5, kk = idx & 31;
      int k = kc*32 + kk;
      Bs[kk][o] = (k < KREAL) ? W[(long)o*KREAL + k] : 0.f;
    }
    __syncthreads();
    #pragma unroll
    for (int kk = 0; kk < 32; ++kk){
      float a[4];
      #pragma unroll
      for (int i = 0; i < 4; ++i) a[i] = As[tm*4+i][kk];
      float4 b0 = *(const float4*)&Bs[kk][tn*8];
      float4 b1 = *(const float4*)&Bs[kk][tn*8+4];
      float bv[8] = {b0.x,b0.y,b0.z,b0.w,b1.x,b1.y,b1.z,b1.w};
      #pragma unroll
      for (int i = 0; i < 4; ++i)
        #pragma unroll
        for (int j = 0; j < 8; ++j) acc[i][j] += a[i]*bv[j];
    }
    __syncthreads();
  }
  #pragma unroll
  for (int i = 0; i < 4; ++i){
    long g = chunk_base + m0 + tm*4 + i;
    #pragma unroll
    for (int j = 0; j < 8; ++j){
      int o = tn*8 + j;
      outp[g*row_stride + col_off + o] = lrelu(acc[i][j] + bias[o]);
    }
  }
}

// ---------------- mlp2: [32768x128] @ W[64][128]^T -> d_out [b][64][n] ------
__global__ __launch_bounds__(256) void mlp2_kernel(
    const float* __restrict__ h1, const float* __restrict__ W,
    const float* __restrict__ bias, float* __restrict__ fout){
  __shared__ __align__(16) float As[64][33];
  __shared__ __align__(16) float Bs[32][68];
  int t = threadIdx.x;
  int m0 = blockIdx.x * 64;
  int tm = t >> 4, tn = t & 15;
  float acc[4][4];
  #pragma unroll
  for (int i = 0; i < 4; ++i)
    #pragma unroll
    for (int j = 0; j < 4; ++j) acc[i][j] = 0.f;

  for (int kc = 0; kc < 4; ++kc){
    #pragma unroll
    for (int r = 0; r < 8; ++r){
      int idx = t + r*256;
      int pt = idx >> 5, kk = idx & 31;
      As[pt][kk] = h1[(long)(m0+pt)*128 + kc*32 + kk];
    }
    #pragma unroll
    for (int r = 0; r < 8; ++r){
      int idx = t + r*256;
      int o = idx >> 5, kk = idx & 31;
      Bs[kk][o] = W[(long)o*128 + kc*32 + kk];
    }
    __syncthreads();
    #pragma unroll
    for (int kk = 0; kk < 32; ++kk){
      float a[4];
      #pragma unroll
      for (int i = 0; i < 4; ++i) a[i] = As[tm*4+i][kk];
      float4 b0 = *(const float4*)&Bs[kk][tn*4];
      float bv[4] = {b0.x,b0.y,b0.z,b0.w};
      #pragma unroll
      for (int i = 0; i < 4; ++i)
        #pragma unroll
        for (int j = 0; j < 4; ++j) acc[i][j] += a[i]*bv[j];
    }
    __syncthreads();
  }
  #pragma unroll
  for (int i = 0; i < 4; ++i){
    long g = m0 + tm*4 + i;
    int b = (int)(g >> 13), n = (int)(g & 8191);
    #pragma unroll
    for (int j = 0; j < 4; ++j){
      int o = tn*4 + j;
      fout[(long)b*64*NPTS + (long)o*NPTS + n] = lrelu(acc[i][j] + bias[o]);
    }
  }
}

// ---------------- flow head: [3][64] @ f -----------------------------------
__global__ __launch_bounds__(256) void flow_kernel(
    const float* __restrict__ f, const float* __restrict__ W,
    const float* __restrict__ bias, float* __restrict__ flow){
  long g = (long)blockIdx.x*256 + threadIdx.x;
  int b = (int)(g >> 13), n = (int)(g & 8191);
  float a0 = bias[0], a1 = bias[1], a2 = bias[2];
  const float* fb = f + (long)b*64*NPTS + n;
  #pragma unroll
  for (int c = 0; c < 64; ++c){
    float v = fb[(long)c*NPTS];
    a0 += v * W[c];
    a1 += v * W[64 + c];
    a2 += v * W[128 + c];
  }
  flow[((long)b*3 + 0)*NPTS + n] = a0;
  flow[((long)b*3 + 1)*NPTS + n] = a1;
  flow[((long)b*3 + 2)*NPTS + n] = a2;
}

extern "C" void kernel_launch(void* const* d_in, const int* in_sizes, int n_in,
                              void* d_out, int out_size, void* d_ws, size_t ws_size,
                              hipStream_t stream){
  const float* xyz    = (const float*)d_in[0];
  const float* feat   = (const float*)d_in[1];
  const int*   knn    = (const int*)  d_in[2];
  const float* w_wn1  = (const float*)d_in[3];
  const float* b_wn1  = (const float*)d_in[4];
  const float* w_lin1 = (const float*)d_in[5];
  const float* b_lin1 = (const float*)d_in[6];
  const float* w_wn2  = (const float*)d_in[7];
  const float* b_wn2  = (const float*)d_in[8];
  const float* w_lin2 = (const float*)d_in[9];
  const float* b_lin2 = (const float*)d_in[10];
  const float* w_mlp1 = (const float*)d_in[11];
  const float* b_mlp1 = (const float*)d_in[12];
  const float* w_mlp2 = (const float*)d_in[13];
  const float* b_mlp2 = (const float*)d_in[14];
  const float* w_last = (const float*)d_in[15];
  const float* b_last = (const float*)d_in[16];
  float* out = (float*)d_out;
  float* ws  = (float*)d_ws;

  // ws layout (floats): fT1 [32768][264], fT2 [32768][136],
  // agg [2048][2080] (reused per chunk/layer), feat2 [32768][128], h1 [32768][128]
  float* fT1   = ws;
  float* fT2   = fT1 + (long)PTS*264;        //  8,650,752
  float* aggb  = fT2 + (long)PTS*136;        // +4,456,448
  float* feat2 = aggb + (long)CHUNK*2080;    // +4,259,840
  float* h1    = feat2 + (long)PTS*128;      // +4,194,304
  // total = 25,755,648 floats = 103 MB                       (+4,194,304 for h1)

  xyz_fill_kernel<<<PTS/256, 256, 0, stream>>>(xyz, fT1, fT2);
  transpose_feat_kernel<<<dim3(128,4,4), 256, 0, stream>>>(feat, fT1);

  // point-conv 1: 259 ch, row stride 264, K = 2072 (pad 2080)
  for (int c = 0; c < PTS/CHUNK; ++c){
    agg_kernel<259,264,2080><<<CHUNK/4, 256, 0, stream>>>(fT1, knn, w_wn1, b_wn1, aggb, c*CHUNK);
    lin_kernel<2080,2072><<<CHUNK/64, 256, 0, stream>>>(aggb, w_lin1, b_lin1, fT2, 136, 3, (long)c*CHUNK);
  }
  // point-conv 2: 131 ch, row stride 136, K = 1048 (pad 1056)
  for (int c = 0; c < PTS/CHUNK; ++c){
    agg_kernel<131,136,1056><<<CHUNK/4, 256, 0, stream>>>(fT2, knn, w_wn2, b_wn2, aggb, c*CHUNK);
    lin_kernel<1056,1048><<<CHUNK/64, 256, 0, stream>>>(aggb, w_lin2, b_lin2, feat2, 128, 0, (long)c*CHUNK);
  }
  // mlp1 128->128
  lin_kernel<128,128><<<PTS/64, 256, 0, stream>>>(feat2, w_mlp1, b_mlp1, h1, 128, 0, 0);
  // mlp2 128->64 -> output f in [B][64][N]
  mlp2_kernel<<<PTS/64, 256, 0, stream>>>(h1, w_mlp2, b_mlp2, out);
  // flow head
  flow_kernel<<<PTS/256, 256, 0, stream>>>(out, w_last, b_last, out + (long)NB*64*NPTS);
}

// Round 3
// 535.852 us; speedup vs baseline: 20.3450x; 20.3450x over previous
//
#include <hip/hip_runtime.h>

#define NPTS 8192
#define PTS 32768

typedef unsigned short u16;
typedef __attribute__((ext_vector_type(8))) short bf16x8;
typedef __attribute__((ext_vector_type(4))) float f32x4;

__device__ __forceinline__ float lrelu(float x){ return x >= 0.f ? x : 0.1f*x; }
__device__ __forceinline__ u16 f2bf(float x){
  unsigned u = __float_as_uint(x);
  return (u16)((u + 0x7FFFu + ((u>>16)&1u)) >> 16);
}
__device__ __forceinline__ float bf2f(u16 h){ return __uint_as_float(((unsigned)h)<<16); }

// ---- xyz fill: fT1 cols 0..2 (bf16), fT2 cols 128..130 (bf16) --------------
__global__ __launch_bounds__(256) void xyz_fill_kernel(
    const float* __restrict__ xyz, u16* __restrict__ fT1, u16* __restrict__ fT2){
  long g = (long)blockIdx.x*256 + threadIdx.x;
  int b = (int)(g >> 13), n = (int)(g & 8191);
  #pragma unroll
  for (int j = 0; j < 3; ++j){
    u16 v = f2bf(xyz[((long)b*3 + j)*NPTS + n]);
    fT1[g*264 + j] = v;
    fT2[g*136 + 128 + j] = v;
  }
}

// ---- transpose feat [B][256][N] -> fT1 rows [g][264] cols 3..258 (bf16) ----
__global__ __launch_bounds__(256) void transpose_feat_kernel(
    const float* __restrict__ feat, u16* __restrict__ fT1){
  __shared__ float tile[64][65];
  int bx = blockIdx.x, by = blockIdx.y, bz = blockIdx.z;
  int t = threadIdx.x;
  int x = t & 63, y4 = t >> 6;
  const float* src = feat + ((long)bz*256 + by*64)*NPTS + (long)bx*64;
  #pragma unroll
  for (int i = 0; i < 16; ++i){
    int c = y4 + i*4;
    tile[c][x] = src[(long)c*NPTS + x];
  }
  __syncthreads();
  u16* dst = fT1 + ((long)bz*NPTS + (long)bx*64)*264 + 3 + by*64;
  #pragma unroll
  for (int i = 0; i < 16; ++i){
    int p = y4 + i*4;
    dst[(long)p*264 + x] = f2bf(tile[x][p]);
  }
}

// ---- weight prep: Bt[o][k] bf16, zero-padded to KP -------------------------
__global__ void prep_bt_kernel(const float* __restrict__ W, u16* __restrict__ Bt,
                               int KP, int KREAL){
  int o = blockIdx.y;
  int k = blockIdx.x*256 + threadIdx.x;
  if (k < KP)
    Bt[(long)o*KP + k] = (k < KREAL) ? f2bf(W[(long)o*KREAL + k]) : (u16)0;
}

// layer2 channel permute: our c: 0..127 feat (ref c+3), 128..130 xyz (ref c-128)
__global__ void prep_bt2_kernel(const float* __restrict__ W, u16* __restrict__ Bt){
  int o = blockIdx.y;
  int k = blockIdx.x*256 + threadIdx.x;
  if (k >= 1088) return;
  int c = k >> 3, m = k & 7;
  u16 v = 0;
  if (c < 128)      v = f2bf(W[(long)o*1048 + (c+3)*8 + m]);
  else if (c < 131) v = f2bf(W[(long)o*1048 + (c-128)*8 + m]);
  Bt[(long)o*1088 + k] = v;
}

// ---- aggregation: one wave per point, bf16 out -----------------------------
template<int CREAL, int S, int KP>
__global__ __launch_bounds__(256) void agg_kernel(
    const u16* __restrict__ fT, const float* __restrict__ xyz,
    const int* __restrict__ knn, const float* __restrict__ w_wn,
    const float* __restrict__ b_wn, u16* __restrict__ aggout, long chunk_base){
  __shared__ float wk_lds[4][16][8];
  int wave = threadIdx.x >> 6, lane = threadIdx.x & 63;
  long p_local = (long)blockIdx.x*4 + wave;
  long g = chunk_base + p_local;
  int b = (int)(g >> 13), n = (int)(g & 8191);
  float cx = xyz[((long)b*3+0)*NPTS + n];
  float cy = xyz[((long)b*3+1)*NPTS + n];
  float cz = xyz[((long)b*3+2)*NPTS + n];
  int idx_lane = knn[(((long)b<<13) + n)*16 + (lane & 15)];
  float vx = 0.f;
  if (lane < 48) vx = xyz[((long)b*3 + (lane>>4))*NPTS + idx_lane];
  int kq = lane & 15;
  float px = __shfl(vx, kq)      - cx;
  float py = __shfl(vx, 16 + kq) - cy;
  float pz = __shfl(vx, 32 + kq) - cz;
  if (lane < 16){
    #pragma unroll
    for (int m = 0; m < 8; ++m){
      float v = w_wn[m*3+0]*px + w_wn[m*3+1]*py + w_wn[m*3+2]*pz + b_wn[m];
      wk_lds[wave][lane][m] = lrelu(v);
    }
  }
  __syncthreads();
  constexpr int NS = (CREAL + 63)/64;
  float acc[NS][8];
  #pragma unroll
  for (int s = 0; s < NS; ++s)
    #pragma unroll
    for (int m = 0; m < 8; ++m) acc[s][m] = 0.f;

  for (int k = 0; k < 16; ++k){
    int idx = __shfl(idx_lane, k);
    const u16* nr = fT + ((long)(b<<13) + idx)*S;
    float wr[8];
    #pragma unroll
    for (int m = 0; m < 8; ++m) wr[m] = wk_lds[wave][k][m];
    #pragma unroll
    for (int s = 0; s < NS; ++s){
      int c = lane + s*64;
      if ((s+1)*64 <= CREAL || c < CREAL){
        float fg = bf2f(nr[c]);
        #pragma unroll
        for (int m = 0; m < 8; ++m) acc[s][m] += fg * wr[m];
      }
    }
  }
  u16* outr = aggout + p_local*KP;
  #pragma unroll
  for (int s = 0; s < NS; ++s){
    int c = lane + s*64;
    if ((s+1)*64 <= CREAL || c < CREAL){
      uint4 u;
      u.x = (unsigned)f2bf(acc[s][0]) | ((unsigned)f2bf(acc[s][1]) << 16);
      u.y = (unsigned)f2bf(acc[s][2]) | ((unsigned)f2bf(acc[s][3]) << 16);
      u.z = (unsigned)f2bf(acc[s][4]) | ((unsigned)f2bf(acc[s][5]) << 16);
      u.w = (unsigned)f2bf(acc[s][6]) | ((unsigned)f2bf(acc[s][7]) << 16);
      *(uint4*)(outr + (long)c*8) = u;
    }
  }
}

// ---- MFMA GEMM: C[m][o] = lrelu(sum_k A[m][k]*Bt[o][k] + bias[o]) ----------
// BM=64, BN=128 (4 waves x 64x32) or BN=64 (4 waves x 32x32).
// OUTMODE 0: bf16 row-major [g][out_stride]; OUTMODE 1: f32 [b][64][n] (d_out).
template<int BN, int OUTMODE>
__global__ __launch_bounds__(256) void mfma_lin_kernel(
    const u16* __restrict__ A, const u16* __restrict__ Bt,
    const float* __restrict__ bias, void* __restrict__ outp,
    int K, long chunk_base, int out_stride){
  __shared__ __align__(16) u16 As[64][72];
  __shared__ __align__(16) u16 Bs[BN][72];
  constexpr int FM = (BN == 128) ? 4 : 2;
  int t = threadIdx.x;
  int w = t >> 6, l = t & 63;
  int ln = l & 15, lh = l >> 4;
  int m0 = blockIdx.x * 64;
  int MOFF = (BN == 128) ? 0 : (w >> 1)*32;
  int o0   = (BN == 128) ? w*32 : (w & 1)*32;
  int srow = t >> 3;             // 0..31
  int scol = (t & 7) * 8;        // element offset 0..56 (16B granules)

  f32x4 acc[FM][2];
  #pragma unroll
  for (int i = 0; i < FM; ++i)
    #pragma unroll
    for (int j = 0; j < 2; ++j) acc[i][j] = (f32x4){0.f,0.f,0.f,0.f};

  int nkc = K >> 6;
  for (int kc = 0; kc < nkc; ++kc){
    // each 64-el row staged by 8 threads x 8 el (16B each)
    uint4 a0 = *(const uint4*)(A + (long)(m0 + srow)*K      + kc*64 + scol);
    uint4 a1 = *(const uint4*)(A + (long)(m0 + srow + 32)*K + kc*64 + scol);
    uint4 bv[BN/32];
    #pragma unroll
    for (int r = 0; r < BN/32; ++r)
      bv[r] = *(const uint4*)(Bt + (long)(srow + r*32)*K + kc*64 + scol);
    __syncthreads();
    *(uint4*)&As[srow][scol]      = a0;
    *(uint4*)&As[srow + 32][scol] = a1;
    #pragma unroll
    for (int r = 0; r < BN/32; ++r)
      *(uint4*)&Bs[srow + r*32][scol] = bv[r];
    __syncthreads();
    #pragma unroll
    for (int kk = 0; kk < 2; ++kk){
      int koff = kk*32 + lh*8;
      bf16x8 af[FM], bfr[2];
      #pragma unroll
      for (int fm = 0; fm < FM; ++fm)
        af[fm] = *(const bf16x8*)&As[MOFF + fm*16 + ln][koff];
      #pragma unroll
      for (int fn = 0; fn < 2; ++fn)
        bfr[fn] = *(const bf16x8*)&Bs[o0 + fn*16 + ln][koff];
      #pragma unroll
      for (int fm = 0; fm < FM; ++fm)
        #pragma unroll
        for (int fn = 0; fn < 2; ++fn)
          acc[fm][fn] = __builtin_amdgcn_mfma_f32_16x16x32_bf16(af[fm], bfr[fn], acc[fm][fn], 0, 0, 0);
    }
  }

  if (OUTMODE == 0){
    __shared__ u16 Cs[64*128];
    float bia[2];
    #pragma unroll
    for (int fn = 0; fn < 2; ++fn) bia[fn] = bias[o0 + fn*16 + ln];
    __syncthreads();
    #pragma unroll
    for (int fm = 0; fm < FM; ++fm)
      #pragma unroll
      for (int fn = 0; fn < 2; ++fn)
        #pragma unroll
        for (int r = 0; r < 4; ++r){
          int row = MOFF + fm*16 + lh*4 + r;
          int col = o0 + fn*16 + ln;
          Cs[row*128 + col] = f2bf(lrelu(acc[fm][fn][r] + bia[fn]));
        }
    __syncthreads();
    int r2 = t >> 2, s2 = t & 3;
    u16* dst = (u16*)outp + (chunk_base + m0 + r2)*(long)out_stride + s2*32;
    #pragma unroll
    for (int q = 0; q < 4; ++q)
      *(uint4*)(dst + q*8) = *(uint4*)&Cs[r2*128 + s2*32 + q*8];
  } else {
    float* outf = (float*)outp;
    #pragma unroll
    for (int fm = 0; fm < FM; ++fm)
      #pragma unroll
      for (int fn = 0; fn < 2; ++fn){
        long gp = chunk_base + m0 + MOFF + fm*16 + lh*4;
        int bb = (int)(gp >> 13), nn = (int)(gp & 8191);
        int col = o0 + fn*16 + ln;
        float bia = bias[col];
        float4 v;
        v.x = lrelu(acc[fm][fn][0] + bia);
        v.y = lrelu(acc[fm][fn][1] + bia);
        v.z = lrelu(acc[fm][fn][2] + bia);
        v.w = lrelu(acc[fm][fn][3] + bia);
        *(float4*)(outf + ((long)(bb*64 + col) << 13) + nn) = v;
      }
  }
}

// ---- flow head: [3][64] @ f ------------------------------------------------
__global__ __launch_bounds__(256) void flow_kernel(
    const float* __restrict__ f, const float* __restrict__ W,
    const float* __restrict__ bias, float* __restrict__ flow){
  long g = (long)blockIdx.x*256 + threadIdx.x;
  int b = (int)(g >> 13), n = (int)(g & 8191);
  float a0 = bias[0], a1 = bias[1], a2 = bias[2];
  const float* fb = f + (long)b*64*NPTS + n;
  #pragma unroll
  for (int c = 0; c < 64; ++c){
    float v = fb[(long)c*NPTS];
    a0 += v * W[c];
    a1 += v * W[64 + c];
    a2 += v * W[128 + c];
  }
  flow[((long)b*3 + 0)*NPTS + n] = a0;
  flow[((long)b*3 + 1)*NPTS + n] = a1;
  flow[((long)b*3 + 2)*NPTS + n] = a2;
}

extern "C" void kernel_launch(void* const* d_in, const int* in_sizes, int n_in,
                              void* d_out, int out_size, void* d_ws, size_t ws_size,
                              hipStream_t stream){
  const float* xyz    = (const float*)d_in[0];
  const float* feat   = (const float*)d_in[1];
  const int*   knn    = (const int*)  d_in[2];
  const float* w_wn1  = (const float*)d_in[3];
  const float* b_wn1  = (const float*)d_in[4];
  const float* w_lin1 = (const float*)d_in[5];
  const float* b_lin1 = (const float*)d_in[6];
  const float* w_wn2  = (const float*)d_in[7];
  const float* b_wn2  = (const float*)d_in[8];
  const float* w_lin2 = (const float*)d_in[9];
  const float* b_lin2 = (const float*)d_in[10];
  const float* w_mlp1 = (const float*)d_in[11];
  const float* b_mlp1 = (const float*)d_in[12];
  const float* w_mlp2 = (const float*)d_in[13];
  const float* b_mlp2 = (const float*)d_in[14];
  const float* w_last = (const float*)d_in[15];
  const float* b_last = (const float*)d_in[16];
  float* out = (float*)d_out;

  char* p = (char*)d_ws;
  auto carve = [&](size_t bytes)->char*{
    char* r = p; p += (bytes + 255) & ~(size_t)255; return r;
  };
  u16* fT1   = (u16*)carve((size_t)PTS*264*2);
  u16* fT2   = (u16*)carve((size_t)PTS*136*2);
  u16* Bt1   = (u16*)carve((size_t)128*2112*2);
  u16* Bt2   = (u16*)carve((size_t)128*1088*2);
  u16* Bm1   = (u16*)carve((size_t)128*128*2);
  u16* Bm2   = (u16*)carve((size_t)64*128*2);
  u16* feat2 = (u16*)carve((size_t)PTS*128*2);
  u16* h1    = (u16*)carve((size_t)PTS*128*2);
  size_t used = (size_t)(p - (char*)d_ws);
  size_t avail = ws_size > used ? ws_size - used : 0;
  u16* aggb = (u16*)p;
  int nc1 = 1; while (nc1 < 64 && (size_t)(PTS/nc1)*2112*2 > avail) nc1 <<= 1;
  int nc2 = 1; while (nc2 < 64 && (size_t)(PTS/nc2)*1088*2 > avail) nc2 <<= 1;

  xyz_fill_kernel<<<PTS/256, 256, 0, stream>>>(xyz, fT1, fT2);
  transpose_feat_kernel<<<dim3(128,4,4), 256, 0, stream>>>(feat, fT1);
  prep_bt_kernel<<<dim3(9,128), 256, 0, stream>>>(w_lin1, Bt1, 2112, 2072);
  prep_bt2_kernel<<<dim3(5,128), 256, 0, stream>>>(w_lin2, Bt2);
  prep_bt_kernel<<<dim3(1,128), 256, 0, stream>>>(w_mlp1, Bm1, 128, 128);
  prep_bt_kernel<<<dim3(1,64),  256, 0, stream>>>(w_mlp2, Bm2, 128, 128);

  int CP1 = PTS/nc1;
  for (long base = 0; base < PTS; base += CP1){
    agg_kernel<259,264,2112><<<CP1/4, 256, 0, stream>>>(fT1, xyz, knn, w_wn1, b_wn1, aggb, base);
    mfma_lin_kernel<128,0><<<CP1/64, 256, 0, stream>>>(aggb, Bt1, b_lin1, fT2, 2112, base, 136);
  }
  int CP2 = PTS/nc2;
  for (long base = 0; base < PTS; base += CP2){
    agg_kernel<131,136,1088><<<CP2/4, 256, 0, stream>>>(fT2, xyz, knn, w_wn2, b_wn2, aggb, base);
    mfma_lin_kernel<128,0><<<CP2/64, 256, 0, stream>>>(aggb, Bt2, b_lin2, feat2, 1088, base, 128);
  }
  mfma_lin_kernel<128,0><<<PTS/64, 256, 0, stream>>>(feat2, Bm1, b_mlp1, h1, 128, 0, 128);
  mfma_lin_kernel<64,1><<<PTS/64, 256, 0, stream>>>(h1, Bm2, b_mlp2, out, 128, 0, 0);
  flow_kernel<<<PTS/256, 256, 0, stream>>>(out, w_last, b_last, out + (long)4*64*NPTS);
}

// Round 4
// 450.491 us; speedup vs baseline: 24.2000x; 1.1895x over previous
//
#include <hip/hip_runtime.h>

#define NPTS 8192
#define PTS 32768

typedef unsigned short u16;
typedef __attribute__((ext_vector_type(8))) short bf16x8;
typedef __attribute__((ext_vector_type(4))) float f32x4;

__device__ __forceinline__ float lrelu(float x){ return x >= 0.f ? x : 0.1f*x; }
__device__ __forceinline__ u16 f2bf(float x){
  unsigned u = __float_as_uint(x);
  return (u16)((u + 0x7FFFu + ((u>>16)&1u)) >> 16);
}
__device__ __forceinline__ float bf2f(u16 h){ return __uint_as_float(((unsigned)h)<<16); }

// ---- xyz fill: fT1 cols 0..2 + zero pad 259..263; fT2 cols 128..135 -------
__global__ __launch_bounds__(256) void xyz_fill_kernel(
    const float* __restrict__ xyz, u16* __restrict__ fT1, u16* __restrict__ fT2){
  long g = (long)blockIdx.x*256 + threadIdx.x;
  int b = (int)(g >> 13), n = (int)(g & 8191);
  u16 v[3];
  #pragma unroll
  for (int j = 0; j < 3; ++j) v[j] = f2bf(xyz[((long)b*3 + j)*NPTS + n]);
  fT1[g*264 + 0] = v[0]; fT1[g*264 + 1] = v[1]; fT1[g*264 + 2] = v[2];
  #pragma unroll
  for (int j = 259; j < 264; ++j) fT1[g*264 + j] = 0;
  uint4 u;
  u.x = (unsigned)v[0] | ((unsigned)v[1] << 16);
  u.y = (unsigned)v[2];
  u.z = 0; u.w = 0;
  *(uint4*)(fT2 + g*136 + 128) = u;
}

// ---- transpose feat [B][256][N] -> fT1 rows [g][264] cols 3..258 (bf16) ----
__global__ __launch_bounds__(256) void transpose_feat_kernel(
    const float* __restrict__ feat, u16* __restrict__ fT1){
  __shared__ float tile[64][65];
  int bx = blockIdx.x, by = blockIdx.y, bz = blockIdx.z;
  int t = threadIdx.x;
  int x = t & 63, y4 = t >> 6;
  const float* src = feat + ((long)bz*256 + by*64)*NPTS + (long)bx*64;
  #pragma unroll
  for (int i = 0; i < 16; ++i){
    int c = y4 + i*4;
    tile[c][x] = src[(long)c*NPTS + x];
  }
  __syncthreads();
  u16* dst = fT1 + ((long)bz*NPTS + (long)bx*64)*264 + 3 + by*64;
  #pragma unroll
  for (int i = 0; i < 16; ++i){
    int p = y4 + i*4;
    dst[(long)p*264 + x] = f2bf(tile[x][p]);
  }
}

// ---- weight prep: Bt[o][k] bf16, zero-padded to KP -------------------------
__global__ void prep_bt_kernel(const float* __restrict__ W, u16* __restrict__ Bt,
                               int KP, int KREAL){
  int o = blockIdx.y;
  int k = blockIdx.x*256 + threadIdx.x;
  if (k < KP)
    Bt[(long)o*KP + k] = (k < KREAL) ? f2bf(W[(long)o*KREAL + k]) : (u16)0;
}

// layer2 channel permute: our c: 0..127 feat (ref c+3), 128..130 xyz (ref c-128)
__global__ void prep_bt2_kernel(const float* __restrict__ W, u16* __restrict__ Bt){
  int o = blockIdx.y;
  int k = blockIdx.x*256 + threadIdx.x;
  if (k >= 1088) return;
  int c = k >> 3, m = k & 7;
  u16 v = 0;
  if (c < 128)      v = f2bf(W[(long)o*1048 + (c+3)*8 + m]);
  else if (c < 131) v = f2bf(W[(long)o*1048 + (c-128)*8 + m]);
  Bt[(long)o*1088 + k] = v;
}

// ---- fused PointConv: gather + weightnet-agg + MFMA GEMM -------------------
// Block: 64 points x 128 outs. S = fT row stride (u16), K = S*8, NCH = S/8.
// outp rows [g][out_stride] cols 0..127 (bf16).
template<int S>
__global__ __launch_bounds__(256, 2) void fused_pc_kernel(
    const u16* __restrict__ fT, const float* __restrict__ xyz,
    const int* __restrict__ knn, const float* __restrict__ w_wn,
    const float* __restrict__ b_wn, const u16* __restrict__ Bt,
    const float* __restrict__ bias, u16* __restrict__ outp, int out_stride){
  constexpr int K   = S*8;
  constexpr int NCH = S/8;
  __shared__ __align__(16) u16   As[64][72];        //  9216 B
  __shared__ __align__(16) u16   Bs[128][72];       // 18432 B
  __shared__ __align__(16) float fstage[64][17][8]; // 34816 B (k-padded rows)
  __shared__ __align__(16) u16   wk2[16][512];      // 16384 B  wk2[k][p*8+m]
  __shared__             u16   idx16[64][16];       //  2048 B   => 80896 total

  int t = threadIdx.x;
  int m0 = blockIdx.x*64;
  int b = m0 >> 13;
  long bbase = (long)b << 13;
  int n0 = m0 & 8191;

  // ---- idx staging (one int4 per thread) ----
  {
    int p = t >> 2, q = t & 3;
    int4 iv = *(const int4*)(knn + (((long)bbase + n0 + p)<<4) + q*4);
    idx16[p][q*4+0] = (u16)iv.x; idx16[p][q*4+1] = (u16)iv.y;
    idx16[p][q*4+2] = (u16)iv.z; idx16[p][q*4+3] = (u16)iv.w;
  }
  __syncthreads();

  // ---- wk setup: thread owns point p = t&63, k-quad kb = t>>6 ----
  {
    float wm[8][3], bm[8];
    #pragma unroll
    for (int m = 0; m < 8; ++m){
      wm[m][0] = w_wn[m*3+0]; wm[m][1] = w_wn[m*3+1]; wm[m][2] = w_wn[m*3+2];
      bm[m] = b_wn[m];
    }
    int p = t & 63, kb = t >> 6;
    float cx = xyz[((long)b*3+0)*NPTS + n0 + p];
    float cy = xyz[((long)b*3+1)*NPTS + n0 + p];
    float cz = xyz[((long)b*3+2)*NPTS + n0 + p];
    #pragma unroll
    for (int j = 0; j < 4; ++j){
      int k = kb*4 + j;
      int idx = idx16[p][k];
      float px = xyz[((long)b*3+0)*NPTS + idx] - cx;
      float py = xyz[((long)b*3+1)*NPTS + idx] - cy;
      float pz = xyz[((long)b*3+2)*NPTS + idx] - cz;
      u16 wv[8];
      #pragma unroll
      for (int m = 0; m < 8; ++m){
        float v = wm[m][0]*px + wm[m][1]*py + wm[m][2]*pz + bm[m];
        wv[m] = f2bf(lrelu(v));
      }
      uint4 u;
      u.x = (unsigned)wv[0] | ((unsigned)wv[1] << 16);
      u.y = (unsigned)wv[2] | ((unsigned)wv[3] << 16);
      u.z = (unsigned)wv[4] | ((unsigned)wv[5] << 16);
      u.w = (unsigned)wv[6] | ((unsigned)wv[7] << 16);
      *(uint4*)&wk2[k][p*8] = u;
    }
  }
  // (first in-loop barrier orders wk2 writes vs reads)

  int w = t >> 6, l = t & 63;
  int ln = l & 15, lh = l >> 4;
  int p_sub = l >> 3, m = l & 7;
  int o0 = w*32;

  f32x4 acc[4][2];
  #pragma unroll
  for (int i = 0; i < 4; ++i)
    #pragma unroll
    for (int j = 0; j < 2; ++j) acc[i][j] = (f32x4){0.f,0.f,0.f,0.f};

  for (int ch = 0; ch < NCH; ++ch){
    // ---- stage gathered f rows (f32) : thread owns p = t&63, k-quad ----
    {
      int p = t & 63, kb = t >> 6;
      #pragma unroll
      for (int j = 0; j < 4; ++j){
        int k = kb*4 + j;
        long ridx = bbase + idx16[p][k];
        uint4 v = *(const uint4*)(fT + ridx*S + ch*8);
        f32x4 lo, hi;
        lo[0] = bf2f((u16)(v.x & 0xffff)); lo[1] = bf2f((u16)(v.x >> 16));
        lo[2] = bf2f((u16)(v.y & 0xffff)); lo[3] = bf2f((u16)(v.y >> 16));
        hi[0] = bf2f((u16)(v.z & 0xffff)); hi[1] = bf2f((u16)(v.z >> 16));
        hi[2] = bf2f((u16)(v.w & 0xffff)); hi[3] = bf2f((u16)(v.w >> 16));
        *(f32x4*)&fstage[p][k][0] = lo;
        *(f32x4*)&fstage[p][k][4] = hi;
      }
    }
    // ---- stage Bt chunk [128][64] ----
    #pragma unroll
    for (int j = 0; j < 4; ++j){
      int idx2 = j*256 + t;
      int o = idx2 >> 3, seg = idx2 & 7;
      *(uint4*)&Bs[o][seg*8] = *(const uint4*)(Bt + (long)o*K + ch*64 + seg*8);
    }
    __syncthreads();
    // ---- phase A: agg chunk -> As. lane=(p_sub,m), 2 passes of 8 points ----
    #pragma unroll
    for (int pass = 0; pass < 2; ++pass){
      int p = w*16 + pass*8 + p_sub;
      float a[8];
      #pragma unroll
      for (int c = 0; c < 8; ++c) a[c] = 0.f;
      #pragma unroll
      for (int k = 0; k < 16; ++k){
        f32x4 fA = *(const f32x4*)&fstage[p][k][0];
        f32x4 fB = *(const f32x4*)&fstage[p][k][4];
        float wv = bf2f(wk2[k][p*8 + m]);
        a[0] += fA[0]*wv; a[1] += fA[1]*wv; a[2] += fA[2]*wv; a[3] += fA[3]*wv;
        a[4] += fB[0]*wv; a[5] += fB[1]*wv; a[6] += fB[2]*wv; a[7] += fB[3]*wv;
      }
      #pragma unroll
      for (int c = 0; c < 8; ++c) As[p][c*8 + m] = f2bf(a[c]);
    }
    __syncthreads();
    // ---- MFMA on the chunk (identical layout to verified lin kernel) ----
    #pragma unroll
    for (int kk = 0; kk < 2; ++kk){
      int koff = kk*32 + lh*8;
      bf16x8 af[4], bfr[2];
      #pragma unroll
      for (int fm = 0; fm < 4; ++fm)
        af[fm] = *(const bf16x8*)&As[fm*16 + ln][koff];
      #pragma unroll
      for (int fn = 0; fn < 2; ++fn)
        bfr[fn] = *(const bf16x8*)&Bs[o0 + fn*16 + ln][koff];
      #pragma unroll
      for (int fm = 0; fm < 4; ++fm)
        #pragma unroll
        for (int fn = 0; fn < 2; ++fn)
          acc[fm][fn] = __builtin_amdgcn_mfma_f32_16x16x32_bf16(af[fm], bfr[fn], acc[fm][fn], 0, 0, 0);
    }
    __syncthreads();
  }

  // ---- epilogue (Cs aliases fstage) ----
  u16* Cs = (u16*)fstage;
  float bia[2] = { bias[o0 + ln], bias[o0 + 16 + ln] };
  #pragma unroll
  for (int fm = 0; fm < 4; ++fm)
    #pragma unroll
    for (int fn = 0; fn < 2; ++fn)
      #pragma unroll
      for (int r = 0; r < 4; ++r){
        int row = fm*16 + lh*4 + r;
        int col = o0 + fn*16 + ln;
        Cs[row*128 + col] = f2bf(lrelu(acc[fm][fn][r] + bia[fn]));
      }
  __syncthreads();
  int r2 = t >> 2, s2 = t & 3;
  u16* dst = outp + (long)(m0 + r2)*out_stride + s2*32;
  #pragma unroll
  for (int q = 0; q < 4; ++q)
    *(uint4*)(dst + q*8) = *(uint4*)&Cs[r2*128 + s2*32 + q*8];
}

// ---- MFMA GEMM (round-3 verified): used for mlp1/mlp2 ----------------------
template<int BN, int OUTMODE>
__global__ __launch_bounds__(256) void mfma_lin_kernel(
    const u16* __restrict__ A, const u16* __restrict__ Bt,
    const float* __restrict__ bias, void* __restrict__ outp,
    int K, long chunk_base, int out_stride){
  __shared__ __align__(16) u16 As[64][72];
  __shared__ __align__(16) u16 Bs[BN][72];
  constexpr int FM = (BN == 128) ? 4 : 2;
  int t = threadIdx.x;
  int w = t >> 6, l = t & 63;
  int ln = l & 15, lh = l >> 4;
  int m0 = blockIdx.x * 64;
  int MOFF = (BN == 128) ? 0 : (w >> 1)*32;
  int o0   = (BN == 128) ? w*32 : (w & 1)*32;
  int srow = t >> 3;
  int scol = (t & 7) * 8;

  f32x4 acc[FM][2];
  #pragma unroll
  for (int i = 0; i < FM; ++i)
    #pragma unroll
    for (int j = 0; j < 2; ++j) acc[i][j] = (f32x4){0.f,0.f,0.f,0.f};

  int nkc = K >> 6;
  for (int kc = 0; kc < nkc; ++kc){
    uint4 a0 = *(const uint4*)(A + (long)(m0 + srow)*K      + kc*64 + scol);
    uint4 a1 = *(const uint4*)(A + (long)(m0 + srow + 32)*K + kc*64 + scol);
    uint4 bv[BN/32];
    #pragma unroll
    for (int r = 0; r < BN/32; ++r)
      bv[r] = *(const uint4*)(Bt + (long)(srow + r*32)*K + kc*64 + scol);
    __syncthreads();
    *(uint4*)&As[srow][scol]      = a0;
    *(uint4*)&As[srow + 32][scol] = a1;
    #pragma unroll
    for (int r = 0; r < BN/32; ++r)
      *(uint4*)&Bs[srow + r*32][scol] = bv[r];
    __syncthreads();
    #pragma unroll
    for (int kk = 0; kk < 2; ++kk){
      int koff = kk*32 + lh*8;
      bf16x8 af[FM], bfr[2];
      #pragma unroll
      for (int fm = 0; fm < FM; ++fm)
        af[fm] = *(const bf16x8*)&As[MOFF + fm*16 + ln][koff];
      #pragma unroll
      for (int fn = 0; fn < 2; ++fn)
        bfr[fn] = *(const bf16x8*)&Bs[o0 + fn*16 + ln][koff];
      #pragma unroll
      for (int fm = 0; fm < FM; ++fm)
        #pragma unroll
        for (int fn = 0; fn < 2; ++fn)
          acc[fm][fn] = __builtin_amdgcn_mfma_f32_16x16x32_bf16(af[fm], bfr[fn], acc[fm][fn], 0, 0, 0);
    }
    __syncthreads();
  }

  if (OUTMODE == 0){
    __shared__ u16 Cs[64*128];
    float bia[2];
    #pragma unroll
    for (int fn = 0; fn < 2; ++fn) bia[fn] = bias[o0 + fn*16 + ln];
    __syncthreads();
    #pragma unroll
    for (int fm = 0; fm < FM; ++fm)
      #pragma unroll
      for (int fn = 0; fn < 2; ++fn)
        #pragma unroll
        for (int r = 0; r < 4; ++r){
          int row = MOFF + fm*16 + lh*4 + r;
          int col = o0 + fn*16 + ln;
          Cs[row*128 + col] = f2bf(lrelu(acc[fm][fn][r] + bia[fn]));
        }
    __syncthreads();
    int r2 = t >> 2, s2 = t & 3;
    u16* dst = (u16*)outp + (chunk_base + m0 + r2)*(long)out_stride + s2*32;
    #pragma unroll
    for (int q = 0; q < 4; ++q)
      *(uint4*)(dst + q*8) = *(uint4*)&Cs[r2*128 + s2*32 + q*8];
  } else {
    float* outf = (float*)outp;
    #pragma unroll
    for (int fm = 0; fm < FM; ++fm)
      #pragma unroll
      for (int fn = 0; fn < 2; ++fn){
        long gp = chunk_base + m0 + MOFF + fm*16 + lh*4;
        int bb = (int)(gp >> 13), nn = (int)(gp & 8191);
        int col = o0 + fn*16 + ln;
        float bia = bias[col];
        float4 v;
        v.x = lrelu(acc[fm][fn][0] + bia);
        v.y = lrelu(acc[fm][fn][1] + bia);
        v.z = lrelu(acc[fm][fn][2] + bia);
        v.w = lrelu(acc[fm][fn][3] + bia);
        *(float4*)(outf + ((long)(bb*64 + col) << 13) + nn) = v;
      }
  }
}

// ---- flow head: [3][64] @ f ------------------------------------------------
__global__ __launch_bounds__(256) void flow_kernel(
    const float* __restrict__ f, const float* __restrict__ W,
    const float* __restrict__ bias, float* __restrict__ flow){
  long g = (long)blockIdx.x*256 + threadIdx.x;
  int b = (int)(g >> 13), n = (int)(g & 8191);
  float a0 = bias[0], a1 = bias[1], a2 = bias[2];
  const float* fb = f + (long)b*64*NPTS + n;
  #pragma unroll
  for (int c = 0; c < 64; ++c){
    float v = fb[(long)c*NPTS];
    a0 += v * W[c];
    a1 += v * W[64 + c];
    a2 += v * W[128 + c];
  }
  flow[((long)b*3 + 0)*NPTS + n] = a0;
  flow[((long)b*3 + 1)*NPTS + n] = a1;
  flow[((long)b*3 + 2)*NPTS + n] = a2;
}

extern "C" void kernel_launch(void* const* d_in, const int* in_sizes, int n_in,
                              void* d_out, int out_size, void* d_ws, size_t ws_size,
                              hipStream_t stream){
  const float* xyz    = (const float*)d_in[0];
  const float* feat   = (const float*)d_in[1];
  const int*   knn    = (const int*)  d_in[2];
  const float* w_wn1  = (const float*)d_in[3];
  const float* b_wn1  = (const float*)d_in[4];
  const float* w_lin1 = (const float*)d_in[5];
  const float* b_lin1 = (const float*)d_in[6];
  const float* w_wn2  = (const float*)d_in[7];
  const float* b_wn2  = (const float*)d_in[8];
  const float* w_lin2 = (const float*)d_in[9];
  const float* b_lin2 = (const float*)d_in[10];
  const float* w_mlp1 = (const float*)d_in[11];
  const float* b_mlp1 = (const float*)d_in[12];
  const float* w_mlp2 = (const float*)d_in[13];
  const float* b_mlp2 = (const float*)d_in[14];
  const float* w_last = (const float*)d_in[15];
  const float* b_last = (const float*)d_in[16];
  float* out = (float*)d_out;

  char* p = (char*)d_ws;
  auto carve = [&](size_t bytes)->char*{
    char* r = p; p += (bytes + 255) & ~(size_t)255; return r;
  };
  u16* fT1   = (u16*)carve((size_t)PTS*264*2);
  u16* fT2   = (u16*)carve((size_t)PTS*136*2);
  u16* Bt1   = (u16*)carve((size_t)128*2112*2);
  u16* Bt2   = (u16*)carve((size_t)128*1088*2);
  u16* Bm1   = (u16*)carve((size_t)128*128*2);
  u16* Bm2   = (u16*)carve((size_t)64*128*2);
  u16* feat2 = (u16*)carve((size_t)PTS*128*2);
  u16* h1    = (u16*)carve((size_t)PTS*128*2);

  xyz_fill_kernel<<<PTS/256, 256, 0, stream>>>(xyz, fT1, fT2);
  transpose_feat_kernel<<<dim3(128,4,4), 256, 0, stream>>>(feat, fT1);
  prep_bt_kernel<<<dim3(9,128), 256, 0, stream>>>(w_lin1, Bt1, 2112, 2072);
  prep_bt2_kernel<<<dim3(5,128), 256, 0, stream>>>(w_lin2, Bt2);
  prep_bt_kernel<<<dim3(1,128), 256, 0, stream>>>(w_mlp1, Bm1, 128, 128);
  prep_bt_kernel<<<dim3(1,64),  256, 0, stream>>>(w_mlp2, Bm2, 128, 128);

  // fused pointconv layers (no agg materialization)
  fused_pc_kernel<264><<<PTS/64, 256, 0, stream>>>(fT1, xyz, knn, w_wn1, b_wn1, Bt1, b_lin1, fT2, 136);
  fused_pc_kernel<136><<<PTS/64, 256, 0, stream>>>(fT2, xyz, knn, w_wn2, b_wn2, Bt2, b_lin2, feat2, 128);

  // mlp1 128->128, mlp2 128->64 (f output), flow head
  mfma_lin_kernel<128,0><<<PTS/64, 256, 0, stream>>>(feat2, Bm1, b_mlp1, h1, 128, 0, 128);
  mfma_lin_kernel<64,1><<<PTS/64, 256, 0, stream>>>(h1, Bm2, b_mlp2, out, 128, 0, 0);
  flow_kernel<<<PTS/256, 256, 0, stream>>>(out, w_last, b_last, out + (long)4*64*NPTS);
}

// Round 5
// 449.145 us; speedup vs baseline: 24.2726x; 1.0030x over previous
//
#include <hip/hip_runtime.h>

#define NPTS 8192
#define PTS 32768

typedef unsigned short u16;
typedef __attribute__((ext_vector_type(8))) short bf16x8;
typedef __attribute__((ext_vector_type(4))) float f32x4;

__device__ __forceinline__ float lrelu(float x){ return x >= 0.f ? x : 0.1f*x; }
__device__ __forceinline__ u16 f2bf(float x){
  unsigned u = __float_as_uint(x);
  return (u16)((u + 0x7FFFu + ((u>>16)&1u)) >> 16);
}
__device__ __forceinline__ float bf2f(u16 h){ return __uint_as_float(((unsigned)h)<<16); }

// ---- xyz fill: fT1 cols 0..2 + zero pad 259..263; fT2 cols 128..135 -------
__global__ __launch_bounds__(256) void xyz_fill_kernel(
    const float* __restrict__ xyz, u16* __restrict__ fT1, u16* __restrict__ fT2){
  long g = (long)blockIdx.x*256 + threadIdx.x;
  int b = (int)(g >> 13), n = (int)(g & 8191);
  u16 v[3];
  #pragma unroll
  for (int j = 0; j < 3; ++j) v[j] = f2bf(xyz[((long)b*3 + j)*NPTS + n]);
  fT1[g*264 + 0] = v[0]; fT1[g*264 + 1] = v[1]; fT1[g*264 + 2] = v[2];
  #pragma unroll
  for (int j = 259; j < 264; ++j) fT1[g*264 + j] = 0;
  uint4 u;
  u.x = (unsigned)v[0] | ((unsigned)v[1] << 16);
  u.y = (unsigned)v[2];
  u.z = 0; u.w = 0;
  *(uint4*)(fT2 + g*136 + 128) = u;
}

// ---- transpose feat [B][256][N] -> fT1 rows [g][264] cols 3..258 (bf16) ----
__global__ __launch_bounds__(256) void transpose_feat_kernel(
    const float* __restrict__ feat, u16* __restrict__ fT1){
  __shared__ float tile[64][65];
  int bx = blockIdx.x, by = blockIdx.y, bz = blockIdx.z;
  int t = threadIdx.x;
  int x = t & 63, y4 = t >> 6;
  const float* src = feat + ((long)bz*256 + by*64)*NPTS + (long)bx*64;
  #pragma unroll
  for (int i = 0; i < 16; ++i){
    int c = y4 + i*4;
    tile[c][x] = src[(long)c*NPTS + x];
  }
  __syncthreads();
  u16* dst = fT1 + ((long)bz*NPTS + (long)bx*64)*264 + 3 + by*64;
  #pragma unroll
  for (int i = 0; i < 16; ++i){
    int p = y4 + i*4;
    dst[(long)p*264 + x] = f2bf(tile[x][p]);
  }
}

// ---- weight prep: Bt[o][k] bf16, zero-padded to KP -------------------------
__global__ void prep_bt_kernel(const float* __restrict__ W, u16* __restrict__ Bt,
                               int KP, int KREAL){
  int o = blockIdx.y;
  int k = blockIdx.x*256 + threadIdx.x;
  if (k < KP)
    Bt[(long)o*KP + k] = (k < KREAL) ? f2bf(W[(long)o*KREAL + k]) : (u16)0;
}

// layer2 channel permute: our c: 0..127 feat (ref c+3), 128..130 xyz (ref c-128)
__global__ void prep_bt2_kernel(const float* __restrict__ W, u16* __restrict__ Bt){
  int o = blockIdx.y;
  int k = blockIdx.x*256 + threadIdx.x;
  if (k >= 1088) return;
  int c = k >> 3, m = k & 7;
  u16 v = 0;
  if (c < 128)      v = f2bf(W[(long)o*1048 + (c+3)*8 + m]);
  else if (c < 131) v = f2bf(W[(long)o*1048 + (c-128)*8 + m]);
  Bt[(long)o*1088 + k] = v;
}

// ---- fused PointConv: gather + weightnet-agg + MFMA GEMM -------------------
// Block: 64 points x 128 outs. S = fT row stride (u16), K = S*8, NCH = S/8.
template<int S>
__global__ __launch_bounds__(256, 2) void fused_pc_kernel(
    const u16* __restrict__ fT, const float* __restrict__ xyz,
    const int* __restrict__ knn, const float* __restrict__ w_wn,
    const float* __restrict__ b_wn, const u16* __restrict__ Bt,
    const float* __restrict__ bias, u16* __restrict__ outp, int out_stride){
  constexpr int K   = S*8;
  constexpr int NCH = S/8;
  __shared__ __align__(16) u16   As[64][72];     //  9216 B
  __shared__ __align__(16) u16   Bs[128][72];    // 18432 B
  __shared__ __align__(16) float fst[64*140];    // 35840 B (row stride 140)
  __shared__ __align__(16) u16   wk2[64][16][8]; // 16384 B  (k swizzled +p)
  // total 79872 B -> 2 blocks/CU

  int t = threadIdx.x;
  int m0 = blockIdx.x*64;
  int b = m0 >> 13;
  long bbase = (long)b << 13;
  int n0 = m0 & 8191;

  int w = t >> 6, l = t & 63;
  int ln = l & 15, lh = l >> 4;
  int o0 = w*32;

  // ---- staging identity: point p = lane, k-quad kb = wave ----
  int p = l, kb = w;
  int4 iv = *(const int4*)(knn + ((long)(bbase + n0 + p))*16 + kb*4);
  int idxs[4] = {iv.x, iv.y, iv.z, iv.w};

  // ---- wk compute -> wk2[p][(k+p)&15][m] (bf16) ----
  {
    float cx = xyz[((long)b*3+0)*NPTS + n0 + p];
    float cy = xyz[((long)b*3+1)*NPTS + n0 + p];
    float cz = xyz[((long)b*3+2)*NPTS + n0 + p];
    float wm[8][3], bm[8];
    #pragma unroll
    for (int m = 0; m < 8; ++m){
      wm[m][0] = w_wn[m*3+0]; wm[m][1] = w_wn[m*3+1]; wm[m][2] = w_wn[m*3+2];
      bm[m] = b_wn[m];
    }
    #pragma unroll
    for (int j = 0; j < 4; ++j){
      int k = kb*4 + j;
      int idx = idxs[j];
      float px = xyz[((long)b*3+0)*NPTS + idx] - cx;
      float py = xyz[((long)b*3+1)*NPTS + idx] - cy;
      float pz = xyz[((long)b*3+2)*NPTS + idx] - cz;
      u16 wv[8];
      #pragma unroll
      for (int m = 0; m < 8; ++m){
        float v = wm[m][0]*px + wm[m][1]*py + wm[m][2]*pz + bm[m];
        wv[m] = f2bf(lrelu(v));
      }
      uint4 u;
      u.x = (unsigned)wv[0] | ((unsigned)wv[1] << 16);
      u.y = (unsigned)wv[2] | ((unsigned)wv[3] << 16);
      u.z = (unsigned)wv[4] | ((unsigned)wv[5] << 16);
      u.w = (unsigned)wv[6] | ((unsigned)wv[7] << 16);
      *(uint4*)&wk2[p][(k + p) & 15][0] = u;
    }
  }

  // ---- Bt staging identity (per j): o = (j*256+t)>>3, seg = (j*256+t)&7 ----
  int bo[4], bseg[4];
  #pragma unroll
  for (int j = 0; j < 4; ++j){
    int idx2 = j*256 + t;
    bo[j] = idx2 >> 3; bseg[j] = (idx2 & 7)*8;
  }

  // ---- prefetch chunk 0 ----
  uint4 ga[4], bb[4];
  #pragma unroll
  for (int j = 0; j < 4; ++j)
    ga[j] = *(const uint4*)(fT + (bbase + idxs[j])*(long)S + 0*8);
  #pragma unroll
  for (int j = 0; j < 4; ++j)
    bb[j] = *(const uint4*)(Bt + (long)bo[j]*K + 0*64 + bseg[j]);

  // ---- phase-A identity: point pA = w*16 + (l>>2), channel pair cp = l&3 ---
  int pA = w*16 + (l >> 2), cp = l & 3;

  f32x4 acc[4][2];
  #pragma unroll
  for (int i = 0; i < 4; ++i)
    #pragma unroll
    for (int j = 0; j < 2; ++j) acc[i][j] = (f32x4){0.f,0.f,0.f,0.f};

  for (int ch = 0; ch < NCH; ++ch){
    // ---- stage prefetched regs -> LDS ----
    #pragma unroll
    for (int j = 0; j < 4; ++j){
      int k = kb*4 + j;
      uint4 v = ga[j];
      f32x4 lo, hi;
      lo[0] = bf2f((u16)(v.x & 0xffff)); lo[1] = bf2f((u16)(v.x >> 16));
      lo[2] = bf2f((u16)(v.y & 0xffff)); lo[3] = bf2f((u16)(v.y >> 16));
      hi[0] = bf2f((u16)(v.z & 0xffff)); hi[1] = bf2f((u16)(v.z >> 16));
      hi[2] = bf2f((u16)(v.w & 0xffff)); hi[3] = bf2f((u16)(v.w >> 16));
      *(f32x4*)&fst[p*140 + k*8 + 0] = lo;
      *(f32x4*)&fst[p*140 + k*8 + 4] = hi;
    }
    #pragma unroll
    for (int j = 0; j < 4; ++j)
      *(uint4*)&Bs[bo[j]][bseg[j]] = bb[j];
    __syncthreads();

    // ---- issue next chunk's loads (latency hidden under phaseA+MFMA) ----
    if (ch + 1 < NCH){
      #pragma unroll
      for (int j = 0; j < 4; ++j)
        ga[j] = *(const uint4*)(fT + (bbase + idxs[j])*(long)S + (ch+1)*8);
      #pragma unroll
      for (int j = 0; j < 4; ++j)
        bb[j] = *(const uint4*)(Bt + (long)bo[j]*K + (ch+1)*64 + bseg[j]);
    }

    // ---- phase A: agg chunk -> As. thread = (pA, cp), m=0..7 in regs ----
    {
      float a0[8], a1[8];
      #pragma unroll
      for (int m = 0; m < 8; ++m){ a0[m] = 0.f; a1[m] = 0.f; }
      #pragma unroll
      for (int k = 0; k < 16; ++k){
        bf16x8 wv = *(const bf16x8*)&wk2[pA][(k + pA) & 15][0];
        const float* fr = &fst[pA*140 + k*8 + cp*2];
        float f0 = fr[0], f1 = fr[1];
        #pragma unroll
        for (int m = 0; m < 8; ++m){
          float wf = bf2f((u16)wv[m]);
          a0[m] += f0*wf;
          a1[m] += f1*wf;
        }
      }
      uint4 u0, u1;
      u0.x = (unsigned)f2bf(a0[0]) | ((unsigned)f2bf(a0[1]) << 16);
      u0.y = (unsigned)f2bf(a0[2]) | ((unsigned)f2bf(a0[3]) << 16);
      u0.z = (unsigned)f2bf(a0[4]) | ((unsigned)f2bf(a0[5]) << 16);
      u0.w = (unsigned)f2bf(a0[6]) | ((unsigned)f2bf(a0[7]) << 16);
      u1.x = (unsigned)f2bf(a1[0]) | ((unsigned)f2bf(a1[1]) << 16);
      u1.y = (unsigned)f2bf(a1[2]) | ((unsigned)f2bf(a1[3]) << 16);
      u1.z = (unsigned)f2bf(a1[4]) | ((unsigned)f2bf(a1[5]) << 16);
      u1.w = (unsigned)f2bf(a1[6]) | ((unsigned)f2bf(a1[7]) << 16);
      *(uint4*)&As[pA][cp*16 + 0] = u0;
      *(uint4*)&As[pA][cp*16 + 8] = u1;
    }
    __syncthreads();

    // ---- MFMA on the chunk ----
    #pragma unroll
    for (int kk = 0; kk < 2; ++kk){
      int koff = kk*32 + lh*8;
      bf16x8 af[4], bfr[2];
      #pragma unroll
      for (int fm = 0; fm < 4; ++fm)
        af[fm] = *(const bf16x8*)&As[fm*16 + ln][koff];
      #pragma unroll
      for (int fn = 0; fn < 2; ++fn)
        bfr[fn] = *(const bf16x8*)&Bs[o0 + fn*16 + ln][koff];
      #pragma unroll
      for (int fm = 0; fm < 4; ++fm)
        #pragma unroll
        for (int fn = 0; fn < 2; ++fn)
          acc[fm][fn] = __builtin_amdgcn_mfma_f32_16x16x32_bf16(af[fm], bfr[fn], acc[fm][fn], 0, 0, 0);
    }
    __syncthreads();
  }

  // ---- epilogue (Cs aliases fst) ----
  u16* Cs = (u16*)fst;
  float bia[2] = { bias[o0 + ln], bias[o0 + 16 + ln] };
  #pragma unroll
  for (int fm = 0; fm < 4; ++fm)
    #pragma unroll
    for (int fn = 0; fn < 2; ++fn)
      #pragma unroll
      for (int r = 0; r < 4; ++r){
        int row = fm*16 + lh*4 + r;
        int col = o0 + fn*16 + ln;
        Cs[row*128 + col] = f2bf(lrelu(acc[fm][fn][r] + bia[fn]));
      }
  __syncthreads();
  int r2 = t >> 2, s2 = t & 3;
  u16* dst = outp + (long)(m0 + r2)*out_stride + s2*32;
  #pragma unroll
  for (int q = 0; q < 4; ++q)
    *(uint4*)(dst + q*8) = *(uint4*)&Cs[r2*128 + s2*32 + q*8];
}

// ---- MFMA GEMM (round-3 verified): used for mlp1/mlp2 ----------------------
template<int BN, int OUTMODE>
__global__ __launch_bounds__(256) void mfma_lin_kernel(
    const u16* __restrict__ A, const u16* __restrict__ Bt,
    const float* __restrict__ bias, void* __restrict__ outp,
    int K, long chunk_base, int out_stride){
  __shared__ __align__(16) u16 As[64][72];
  __shared__ __align__(16) u16 Bs[BN][72];
  constexpr int FM = (BN == 128) ? 4 : 2;
  int t = threadIdx.x;
  int w = t >> 6, l = t & 63;
  int ln = l & 15, lh = l >> 4;
  int m0 = blockIdx.x * 64;
  int MOFF = (BN == 128) ? 0 : (w >> 1)*32;
  int o0   = (BN == 128) ? w*32 : (w & 1)*32;
  int srow = t >> 3;
  int scol = (t & 7) * 8;

  f32x4 acc[FM][2];
  #pragma unroll
  for (int i = 0; i < FM; ++i)
    #pragma unroll
    for (int j = 0; j < 2; ++j) acc[i][j] = (f32x4){0.f,0.f,0.f,0.f};

  int nkc = K >> 6;
  for (int kc = 0; kc < nkc; ++kc){
    uint4 a0 = *(const uint4*)(A + (long)(m0 + srow)*K      + kc*64 + scol);
    uint4 a1 = *(const uint4*)(A + (long)(m0 + srow + 32)*K + kc*64 + scol);
    uint4 bv[BN/32];
    #pragma unroll
    for (int r = 0; r < BN/32; ++r)
      bv[r] = *(const uint4*)(Bt + (long)(srow + r*32)*K + kc*64 + scol);
    __syncthreads();
    *(uint4*)&As[srow][scol]      = a0;
    *(uint4*)&As[srow + 32][scol] = a1;
    #pragma unroll
    for (int r = 0; r < BN/32; ++r)
      *(uint4*)&Bs[srow + r*32][scol] = bv[r];
    __syncthreads();
    #pragma unroll
    for (int kk = 0; kk < 2; ++kk){
      int koff = kk*32 + lh*8;
      bf16x8 af[FM], bfr[2];
      #pragma unroll
      for (int fm = 0; fm < FM; ++fm)
        af[fm] = *(const bf16x8*)&As[MOFF + fm*16 + ln][koff];
      #pragma unroll
      for (int fn = 0; fn < 2; ++fn)
        bfr[fn] = *(const bf16x8*)&Bs[o0 + fn*16 + ln][koff];
      #pragma unroll
      for (int fm = 0; fm < FM; ++fm)
        #pragma unroll
        for (int fn = 0; fn < 2; ++fn)
          acc[fm][fn] = __builtin_amdgcn_mfma_f32_16x16x32_bf16(af[fm], bfr[fn], acc[fm][fn], 0, 0, 0);
    }
    __syncthreads();
  }

  if (OUTMODE == 0){
    __shared__ u16 Cs[64*128];
    float bia[2];
    #pragma unroll
    for (int fn = 0; fn < 2; ++fn) bia[fn] = bias[o0 + fn*16 + ln];
    __syncthreads();
    #pragma unroll
    for (int fm = 0; fm < FM; ++fm)
      #pragma unroll
      for (int fn = 0; fn < 2; ++fn)
        #pragma unroll
        for (int r = 0; r < 4; ++r){
          int row = MOFF + fm*16 + lh*4 + r;
          int col = o0 + fn*16 + ln;
          Cs[row*128 + col] = f2bf(lrelu(acc[fm][fn][r] + bia[fn]));
        }
    __syncthreads();
    int r2 = t >> 2, s2 = t & 3;
    u16* dst = (u16*)outp + (chunk_base + m0 + r2)*(long)out_stride + s2*32;
    #pragma unroll
    for (int q = 0; q < 4; ++q)
      *(uint4*)(dst + q*8) = *(uint4*)&Cs[r2*128 + s2*32 + q*8];
  } else {
    float* outf = (float*)outp;
    #pragma unroll
    for (int fm = 0; fm < FM; ++fm)
      #pragma unroll
      for (int fn = 0; fn < 2; ++fn){
        long gp = chunk_base + m0 + MOFF + fm*16 + lh*4;
        int bb = (int)(gp >> 13), nn = (int)(gp & 8191);
        int col = o0 + fn*16 + ln;
        float bia = bias[col];
        float4 v;
        v.x = lrelu(acc[fm][fn][0] + bia);
        v.y = lrelu(acc[fm][fn][1] + bia);
        v.z = lrelu(acc[fm][fn][2] + bia);
        v.w = lrelu(acc[fm][fn][3] + bia);
        *(float4*)(outf + ((long)(bb*64 + col) << 13) + nn) = v;
      }
  }
}

// ---- flow head: [3][64] @ f ------------------------------------------------
__global__ __launch_bounds__(256) void flow_kernel(
    const float* __restrict__ f, const float* __restrict__ W,
    const float* __restrict__ bias, float* __restrict__ flow){
  long g = (long)blockIdx.x*256 + threadIdx.x;
  int b = (int)(g >> 13), n = (int)(g & 8191);
  float a0 = bias[0], a1 = bias[1], a2 = bias[2];
  const float* fb = f + (long)b*64*NPTS + n;
  #pragma unroll
  for (int c = 0; c < 64; ++c){
    float v = fb[(long)c*NPTS];
    a0 += v * W[c];
    a1 += v * W[64 + c];
    a2 += v * W[128 + c];
  }
  flow[((long)b*3 + 0)*NPTS + n] = a0;
  flow[((long)b*3 + 1)*NPTS + n] = a1;
  flow[((long)b*3 + 2)*NPTS + n] = a2;
}

extern "C" void kernel_launch(void* const* d_in, const int* in_sizes, int n_in,
                              void* d_out, int out_size, void* d_ws, size_t ws_size,
                              hipStream_t stream){
  const float* xyz    = (const float*)d_in[0];
  const float* feat   = (const float*)d_in[1];
  const int*   knn    = (const int*)  d_in[2];
  const float* w_wn1  = (const float*)d_in[3];
  const float* b_wn1  = (const float*)d_in[4];
  const float* w_lin1 = (const float*)d_in[5];
  const float* b_lin1 = (const float*)d_in[6];
  const float* w_wn2  = (const float*)d_in[7];
  const float* b_wn2  = (const float*)d_in[8];
  const float* w_lin2 = (const float*)d_in[9];
  const float* b_lin2 = (const float*)d_in[10];
  const float* w_mlp1 = (const float*)d_in[11];
  const float* b_mlp1 = (const float*)d_in[12];
  const float* w_mlp2 = (const float*)d_in[13];
  const float* b_mlp2 = (const float*)d_in[14];
  const float* w_last = (const float*)d_in[15];
  const float* b_last = (const float*)d_in[16];
  float* out = (float*)d_out;

  char* p = (char*)d_ws;
  auto carve = [&](size_t bytes)->char*{
    char* r = p; p += (bytes + 255) & ~(size_t)255; return r;
  };
  u16* fT1   = (u16*)carve((size_t)PTS*264*2);
  u16* fT2   = (u16*)carve((size_t)PTS*136*2);
  u16* Bt1   = (u16*)carve((size_t)128*2112*2);
  u16* Bt2   = (u16*)carve((size_t)128*1088*2);
  u16* Bm1   = (u16*)carve((size_t)128*128*2);
  u16* Bm2   = (u16*)carve((size_t)64*128*2);
  u16* feat2 = (u16*)carve((size_t)PTS*128*2);
  u16* h1    = (u16*)carve((size_t)PTS*128*2);

  xyz_fill_kernel<<<PTS/256, 256, 0, stream>>>(xyz, fT1, fT2);
  transpose_feat_kernel<<<dim3(128,4,4), 256, 0, stream>>>(feat, fT1);
  prep_bt_kernel<<<dim3(9,128), 256, 0, stream>>>(w_lin1, Bt1, 2112, 2072);
  prep_bt2_kernel<<<dim3(5,128), 256, 0, stream>>>(w_lin2, Bt2);
  prep_bt_kernel<<<dim3(1,128), 256, 0, stream>>>(w_mlp1, Bm1, 128, 128);
  prep_bt_kernel<<<dim3(1,64),  256, 0, stream>>>(w_mlp2, Bm2, 128, 128);

  // fused pointconv layers (no agg materialization)
  fused_pc_kernel<264><<<PTS/64, 256, 0, stream>>>(fT1, xyz, knn, w_wn1, b_wn1, Bt1, b_lin1, fT2, 136);
  fused_pc_kernel<136><<<PTS/64, 256, 0, stream>>>(fT2, xyz, knn, w_wn2, b_wn2, Bt2, b_lin2, feat2, 128);

  // mlp1 128->128, mlp2 128->64 (f output), flow head
  mfma_lin_kernel<128,0><<<PTS/64, 256, 0, stream>>>(feat2, Bm1, b_mlp1, h1, 128, 0, 128);
  mfma_lin_kernel<64,1><<<PTS/64, 256, 0, stream>>>(h1, Bm2, b_mlp2, out, 128, 0, 0);
  flow_kernel<<<PTS/256, 256, 0, stream>>>(out, w_last, b_last, out + (long)4*64*NPTS);
}